// Round 18
// baseline (70.198 us; speedup 1.0000x reference)
//
#include <hip/hip_runtime.h>
#include <hip/hip_bf16.h>
#include <math.h>

#define N_ 8192
#define A_ 512
#define D_ 512
#define NN_ 3
#define KPARTS 8

// ---------------------------------------------------------------------------
// Polynomial GELU — NO transcendentals (round-15 proven; |err| <= 9.5e-3).
// ---------------------------------------------------------------------------
__device__ __forceinline__ float gelu_poly(float x) {
  const float u  = x * x;
  const float s  = fminf(u, 9.0f);
  float p = fmaf(-2.8012e-4f, s, 6.4615e-3f);
  p = fmaf(p, s, -6.1073e-2f);
  p = fmaf(p, s, 3.96693e-1f);
  p = p * s;
  const float ax   = fabsf(x);
  const float e    = fminf(p, 0.5f * ax);
  const float tail = fmaxf(ax - 3.0f, 0.0f);
  return fmaf(0.5f, x, fmaf(0.5f, tail, e));
}

// ---------------------------------------------------------------------------
// Kernel 0: sq[i] = ||a_i||^2. (unchanged)
// ---------------------------------------------------------------------------
__global__ __launch_bounds__(64) void sq_kernel(
    const float* __restrict__ anchors, float* __restrict__ sq) {
  const int i = blockIdx.x;
  const int l = threadIdx.x;
  const float4* a = reinterpret_cast<const float4*>(anchors + (size_t)i * D_);
  float s = 0.f;
  for (int k = l; k < D_ / 4; k += 64) {
    float4 v = a[k];
    s += v.x * v.x + v.y * v.y + v.z * v.z + v.w * v.w;
  }
#pragma unroll
  for (int d = 32; d > 0; d >>= 1) s += __shfl_down(s, d);
  if (l == 0) sq[i] = s;
}

// ---------------------------------------------------------------------------
// Kernel 1: G_z = partial gram over K-part z. (unchanged, KPARTS=8)
// ---------------------------------------------------------------------------
__global__ __launch_bounds__(256) void gram_tiled_kernel(
    const float* __restrict__ anchors, float* __restrict__ G) {
  __shared__ float At[32][68];
  __shared__ float Bt[32][68];

  const int tx = threadIdx.x;
  const int ty = threadIdx.y;
  const int tid = ty * 16 + tx;
  const int i0 = blockIdx.y * 64;
  const int j0 = blockIdx.x * 64;
  const int z  = blockIdx.z;
  float* Gz = G + (size_t)z * A_ * A_;

  const int r0 = tid >> 3;
  const int c4 = tid & 7;

  float acc[4][4];
#pragma unroll
  for (int m = 0; m < 4; ++m)
#pragma unroll
    for (int n = 0; n < 4; ++n) acc[m][n] = 0.f;

  for (int kt = z * (16 / KPARTS); kt < (z + 1) * (16 / KPARTS); ++kt) {
    const int kb = kt * 32 + c4 * 4;
    float4 va = *reinterpret_cast<const float4*>(&anchors[(size_t)(i0 + r0) * D_ + kb]);
    float4 vb = *reinterpret_cast<const float4*>(&anchors[(size_t)(i0 + r0 + 32) * D_ + kb]);
    float4 wa = *reinterpret_cast<const float4*>(&anchors[(size_t)(j0 + r0) * D_ + kb]);
    float4 wb = *reinterpret_cast<const float4*>(&anchors[(size_t)(j0 + r0 + 32) * D_ + kb]);
    __syncthreads();
    const int kc = c4 * 4;
    At[kc + 0][r0] = va.x; At[kc + 1][r0] = va.y; At[kc + 2][r0] = va.z; At[kc + 3][r0] = va.w;
    At[kc + 0][r0 + 32] = vb.x; At[kc + 1][r0 + 32] = vb.y; At[kc + 2][r0 + 32] = vb.z; At[kc + 3][r0 + 32] = vb.w;
    Bt[kc + 0][r0] = wa.x; Bt[kc + 1][r0] = wa.y; Bt[kc + 2][r0] = wa.z; Bt[kc + 3][r0] = wa.w;
    Bt[kc + 0][r0 + 32] = wb.x; Bt[kc + 1][r0 + 32] = wb.y; Bt[kc + 2][r0 + 32] = wb.z; Bt[kc + 3][r0 + 32] = wb.w;
    __syncthreads();

#pragma unroll
    for (int kk = 0; kk < 32; ++kk) {
      float4 a = *reinterpret_cast<const float4*>(&At[kk][ty * 4]);
      float4 b = *reinterpret_cast<const float4*>(&Bt[kk][tx * 4]);
      acc[0][0] += a.x * b.x; acc[0][1] += a.x * b.y; acc[0][2] += a.x * b.z; acc[0][3] += a.x * b.w;
      acc[1][0] += a.y * b.x; acc[1][1] += a.y * b.y; acc[1][2] += a.y * b.z; acc[1][3] += a.y * b.w;
      acc[2][0] += a.z * b.x; acc[2][1] += a.z * b.y; acc[2][2] += a.z * b.z; acc[2][3] += a.z * b.w;
      acc[3][0] += a.w * b.x; acc[3][1] += a.w * b.y; acc[3][2] += a.w * b.z; acc[3][3] += a.w * b.w;
    }
  }

#pragma unroll
  for (int m = 0; m < 4; ++m) {
    float4 st;
    st.x = acc[m][0]; st.y = acc[m][1]; st.z = acc[m][2]; st.w = acc[m][3];
    *reinterpret_cast<float4*>(&Gz[(size_t)(i0 + ty * 4 + m) * A_ + j0 + tx * 4]) = st;
  }
}

// ---------------------------------------------------------------------------
// Kernel 2: per-anchor 3-NN + Cayley-Menger det. (unchanged)
// ---------------------------------------------------------------------------
__device__ __forceinline__ void lexmin(float& v, int& j, float ov, int oj) {
  if (ov < v || (ov == v && oj < j)) { v = ov; j = oj; }
}

__global__ __launch_bounds__(64) void nn_det_kernel(
    const float* __restrict__ G, const float* __restrict__ sq,
    float* __restrict__ quality) {
  __shared__ float d2s[16];
  const int i = blockIdx.x;
  const int l = threadIdx.x;
  const float sqi = sq[i];
  const int jb = l * 8;

  float gg[8] = {0.f, 0.f, 0.f, 0.f, 0.f, 0.f, 0.f, 0.f};
#pragma unroll
  for (int z = 0; z < KPARTS; ++z) {
    const float* Grow = G + (size_t)z * A_ * A_ + (size_t)i * A_;
    float4 g0 = *reinterpret_cast<const float4*>(&Grow[jb]);
    float4 g1 = *reinterpret_cast<const float4*>(&Grow[jb + 4]);
    gg[0] += g0.x; gg[1] += g0.y; gg[2] += g0.z; gg[3] += g0.w;
    gg[4] += g1.x; gg[5] += g1.y; gg[6] += g1.z; gg[7] += g1.w;
  }
  float4 s0 = *reinterpret_cast<const float4*>(&sq[jb]);
  float4 s1 = *reinterpret_cast<const float4*>(&sq[jb + 4]);
  float ss[8] = { s0.x, s0.y, s0.z, s0.w, s1.x, s1.y, s1.z, s1.w };

  float dist[8];
#pragma unroll
  for (int q = 0; q < 8; ++q) {
    float d2 = fmaxf(sqi + ss[q] - 2.f * gg[q], 0.f);
    float dd = sqrtf(d2);
    if (jb + q == i) dd += 1e12f;
    dist[q] = dd;
  }

  int nn[NN_];
#pragma unroll
  for (int r = 0; r < NN_; ++r) {
    float bv = 1e30f;
    int bi = 0x7fffffff;
#pragma unroll
    for (int q = 0; q < 8; ++q) lexmin(bv, bi, dist[q], jb + q);
#pragma unroll
    for (int d = 1; d < 64; d <<= 1) {
      float ov = __shfl_xor(bv, d);
      int oi = __shfl_xor(bi, d);
      lexmin(bv, bi, ov, oi);
    }
    nn[r] = bi;
#pragma unroll
    for (int q = 0; q < 8; ++q)
      if (jb + q == bi) dist[q] = 1e30f;
  }

  if (l < 16) {
    const int p = l >> 2, q = l & 3;
    const int pi = (p == 0) ? i : ((p == 1) ? nn[0] : ((p == 2) ? nn[1] : nn[2]));
    const int qi = (q == 0) ? i : ((q == 1) ? nn[0] : ((q == 2) ? nn[1] : nn[2]));
    float d2f;
    if (p == q) {
      d2f = 0.f;
    } else {
      float g = 0.f;
#pragma unroll
      for (int z = 0; z < KPARTS; ++z)
        g += G[(size_t)z * A_ * A_ + (size_t)pi * A_ + qi];
      d2f = sq[pi] + sq[qi] - 2.f * g;
    }
    d2s[l] = d2f;
  }
  __syncthreads();

  if (l == 0) {
    double M[5][5];
    M[0][0] = 0.0;
    for (int q = 1; q < 5; ++q) { M[0][q] = 1.0; M[q][0] = 1.0; }
    for (int p = 0; p < 4; ++p)
      for (int q = 0; q < 4; ++q)
        M[p + 1][q + 1] = (double)d2s[p * 4 + q];

    double det = 1.0;
    for (int c = 0; c < 5; ++c) {
      int piv = c;
      double mx = fabs(M[c][c]);
      for (int r2 = c + 1; r2 < 5; ++r2) {
        double v = fabs(M[r2][c]);
        if (v > mx) { mx = v; piv = r2; }
      }
      if (piv != c) {
        for (int c2 = 0; c2 < 5; ++c2) { double tmp = M[c][c2]; M[c][c2] = M[piv][c2]; M[piv][c2] = tmp; }
        det = -det;
      }
      double pv = M[c][c];
      det *= pv;
      if (pv == 0.0) break;
      for (int r2 = c + 1; r2 < 5; ++r2) {
        double f = M[r2][c] / pv;
        for (int c2 = c; c2 < 5; ++c2) M[r2][c2] -= f * M[c][c2];
      }
    }
    float raw = (float)det;
    float sg = (raw > 0.f) ? 1.f : ((raw < 0.f) ? -1.f : 0.f);
    quality[i] = sg * logf(fabsf(raw) + 1e-12f);
  }
}

// ---------------------------------------------------------------------------
// Kernel 3: normalize quality. (unchanged)
// ---------------------------------------------------------------------------
__global__ __launch_bounds__(A_) void norm_cm_kernel(
    const float* __restrict__ quality, float* __restrict__ cmn) {
  __shared__ float red[A_];
  const int t = threadIdx.x;
  float q = quality[t];
  red[t] = q;
  __syncthreads();
  for (int s = A_ / 2; s > 0; s >>= 1) {
    if (t < s) red[t] += red[t + s];
    __syncthreads();
  }
  float mean = red[0] * (1.0f / A_);
  __syncthreads();
  float dq = q - mean;
  red[t] = dq * dq;
  __syncthreads();
  for (int s = A_ / 2; s > 0; s >>= 1) {
    if (t < s) red[t] += red[t + s];
    __syncthreads();
  }
  float sd = sqrtf(red[0] * (1.0f / (A_ - 1)));
  sd = fmaxf(sd, 1e-8f);
  cmn[t] = dq / sd;
}

// ---------------------------------------------------------------------------
// Kernel 4: WAVE-PRIVATE fused rank + poly-MLP + sigmoid. ZERO barriers.
// One row per wave64 (8 elems/lane); 4 independent waves per 256-thr block,
// each with a private LDS slice. Same-wave LDS ops execute in order, so the
// histogram->scan->scatter->probe chain needs no __syncthreads. Scan runs
// per-wave via shfl; pref/len packed (prefix<<16|count) in LDS; scatter slot
// via hist-decrement (no cursor array).
// ---------------------------------------------------------------------------
__global__ __launch_bounds__(256) void gate_wave(
    const float* __restrict__ tri, const float* __restrict__ cmn,
    const float* __restrict__ W1, const float* __restrict__ b1,
    const float* __restrict__ W2, const float* __restrict__ b2,
    float* __restrict__ out) {
  __shared__ int hist[4][256];
  __shared__ int pk[4][256];
  __shared__ unsigned long long sorted[4][A_];

  const int w = threadIdx.x >> 6;
  const int l = threadIdx.x & 63;
  const int n = blockIdx.x * 4 + w;
  const size_t rowo = (size_t)n * A_;
  const int e0 = l * 8;

  float4 tv0 = *reinterpret_cast<const float4*>(tri + rowo + e0);
  float4 tv1 = *reinterpret_cast<const float4*>(tri + rowo + e0 + 4);
  const float ti[8] = { tv0.x, tv0.y, tv0.z, tv0.w, tv1.x, tv1.y, tv1.z, tv1.w };

  // init 4 buckets/lane (one b128 store)
  int4 z4; z4.x = 0; z4.y = 0; z4.z = 0; z4.w = 0;
  *reinterpret_cast<int4*>(&hist[w][l * 4]) = z4;
  __builtin_amdgcn_wave_barrier();

  unsigned long long key[8];
  int bb[8];
#pragma unroll
  for (int q = 0; q < 8; ++q) {
    key[q] = ((unsigned long long)__float_as_uint(ti[q]) << 9) | (unsigned)(e0 + q);
    int b = (int)(ti[q] * 128.0f);
    bb[q] = (b < 0) ? 0 : ((b > 255) ? 255 : b);
    atomicAdd(&hist[w][bb[q]], 1);
  }
  __builtin_amdgcn_wave_barrier();

  // per-wave exclusive scan of 256 counts (4/lane + shfl)
  int4 h4 = *reinterpret_cast<const int4*>(&hist[w][l * 4]);
  const int s = h4.x + h4.y + h4.z + h4.w;
  int incl = s;
#pragma unroll
  for (int d = 1; d < 64; d <<= 1) {
    int u = __shfl_up(incl, d);
    if (l >= d) incl += u;
  }
  const int ex = incl - s;
  int4 pkv;
  pkv.x = (ex << 16) | h4.x;
  pkv.y = ((ex + h4.x) << 16) | h4.y;
  pkv.z = ((ex + h4.x + h4.y) << 16) | h4.z;
  pkv.w = ((ex + h4.x + h4.y + h4.z) << 16) | h4.w;
  *reinterpret_cast<int4*>(&pk[w][l * 4]) = pkv;
  __builtin_amdgcn_wave_barrier();

  // scatter: slot = prefix + (remaining-1) via hist decrement
  int start[8], len[8];
#pragma unroll
  for (int q = 0; q < 8; ++q) {
    const int p = pk[w][bb[q]];
    start[q] = p >> 16;
    len[q]   = p & 0xffff;
    const int pos = start[q] + atomicAdd(&hist[w][bb[q]], -1) - 1;
    sorted[w][pos] = key[q];
  }
  __builtin_amdgcn_wave_barrier();

  float4 cv0 = *reinterpret_cast<const float4*>(cmn + e0);
  float4 cv1 = *reinterpret_cast<const float4*>(cmn + e0 + 4);
  const float f0a[8] = { cv0.x, cv0.y, cv0.z, cv0.w, cv1.x, cv1.y, cv1.z, cv1.w };

  float res[8];
#pragma unroll
  for (int q = 0; q < 8; ++q) {
    int cnt = start[q];
    for (int m = 0; m < len[q]; ++m) cnt += (sorted[w][start[q] + m] < key[q]);
    const float rank = (float)cnt * (1.0f / (A_ - 1));
    const float f0 = f0a[q];
    const float f1 = 1.0f - ti[q];

    float logit = b2[0];
#pragma unroll
    for (int k = 0; k < 16; ++k) {
      float x = fmaf(W1[k * 3 + 0], f0,
                fmaf(W1[k * 3 + 1], f1,
                fmaf(W1[k * 3 + 2], rank, b1[k])));
      logit = fmaf(W2[k], gelu_poly(x), logit);
    }
    res[q] = __builtin_amdgcn_rcpf(1.0f + exp2f(logit * -1.44269504088896340736f));
  }

  float4 o0, o1;
  o0.x = res[0]; o0.y = res[1]; o0.z = res[2]; o0.w = res[3];
  o1.x = res[4]; o1.y = res[5]; o1.z = res[6]; o1.w = res[7];
  *reinterpret_cast<float4*>(out + rowo + e0)     = o0;
  *reinterpret_cast<float4*>(out + rowo + e0 + 4) = o1;
}

// ---------------------------------------------------------------------------
extern "C" void kernel_launch(void* const* d_in, const int* in_sizes, int n_in,
                              void* d_out, int out_size, void* d_ws, size_t ws_size,
                              hipStream_t stream) {
  // inputs: 0 embedding (unused), 1 anchors, 2 tri, 3 W1, 4 b1, 5 W2, 6 b2
  const float* anchors = (const float*)d_in[1];
  const float* tri     = (const float*)d_in[2];
  const float* W1      = (const float*)d_in[3];
  const float* b1      = (const float*)d_in[4];
  const float* W2      = (const float*)d_in[5];
  const float* b2      = (const float*)d_in[6];
  float* out = (float*)d_out;

  float* G        = (float*)d_ws;                      // KPARTS*A_*A_ (8 MB)
  float* sq       = G + (size_t)KPARTS * A_ * A_;      // A_
  float* quality  = sq + A_;                           // A_
  float* cmn      = quality + A_;                      // A_

  sq_kernel<<<A_, 64, 0, stream>>>(anchors, sq);
  gram_tiled_kernel<<<dim3(8, 8, KPARTS), dim3(16, 16), 0, stream>>>(anchors, G);
  nn_det_kernel<<<A_, 64, 0, stream>>>(G, sq, quality);
  norm_cm_kernel<<<1, A_, 0, stream>>>(quality, cmn);
  gate_wave<<<N_ / 4, 256, 0, stream>>>(tri, cmn, W1, b1, W2, b2, out);
}

// Round 20
// 59.881 us; speedup vs baseline: 1.1723x; 1.1723x over previous
//
#include <hip/hip_runtime.h>
#include <hip/hip_bf16.h>
#include <math.h>

#define N_ 8192
#define A_ 512
#define D_ 512
#define NN_ 3
#define KPARTS 8

typedef _Float16 h2 __attribute__((ext_vector_type(2)));

// ---------------------------------------------------------------------------
// Kernel 0: sq[i] = ||a_i||^2 (blocks 0..A_-1); block A_ packs MLP weights
// into h2 pairs (w0p[8] w1p[8] w2p[8] b1p[8]) for v_pk_fma_f16.
// ---------------------------------------------------------------------------
__global__ __launch_bounds__(64) void sq_kernel(
    const float* __restrict__ anchors, float* __restrict__ sq,
    const float* __restrict__ W1, const float* __restrict__ b1,
    h2* __restrict__ wpk) {
  const int i = blockIdx.x;
  const int l = threadIdx.x;
  if (i == A_) {
    if (l < 8) {
      h2 a, b, c, d;
      a.x = (_Float16)W1[(2 * l) * 3 + 0]; a.y = (_Float16)W1[(2 * l + 1) * 3 + 0];
      b.x = (_Float16)W1[(2 * l) * 3 + 1]; b.y = (_Float16)W1[(2 * l + 1) * 3 + 1];
      c.x = (_Float16)W1[(2 * l) * 3 + 2]; c.y = (_Float16)W1[(2 * l + 1) * 3 + 2];
      d.x = (_Float16)b1[2 * l];           d.y = (_Float16)b1[2 * l + 1];
      wpk[l] = a; wpk[8 + l] = b; wpk[16 + l] = c; wpk[24 + l] = d;
    }
    return;
  }
  const float4* a = reinterpret_cast<const float4*>(anchors + (size_t)i * D_);
  float s = 0.f;
  for (int k = l; k < D_ / 4; k += 64) {
    float4 v = a[k];
    s += v.x * v.x + v.y * v.y + v.z * v.z + v.w * v.w;
  }
#pragma unroll
  for (int d = 32; d > 0; d >>= 1) s += __shfl_down(s, d);
  if (l == 0) sq[i] = s;
}

// ---------------------------------------------------------------------------
// Kernel 1: G_z = partial gram over K-part z. (unchanged, KPARTS=8)
// ---------------------------------------------------------------------------
__global__ __launch_bounds__(256) void gram_tiled_kernel(
    const float* __restrict__ anchors, float* __restrict__ G) {
  __shared__ float At[32][68];
  __shared__ float Bt[32][68];

  const int tx = threadIdx.x;
  const int ty = threadIdx.y;
  const int tid = ty * 16 + tx;
  const int i0 = blockIdx.y * 64;
  const int j0 = blockIdx.x * 64;
  const int z  = blockIdx.z;
  float* Gz = G + (size_t)z * A_ * A_;

  const int r0 = tid >> 3;
  const int c4 = tid & 7;

  float acc[4][4];
#pragma unroll
  for (int m = 0; m < 4; ++m)
#pragma unroll
    for (int n = 0; n < 4; ++n) acc[m][n] = 0.f;

  for (int kt = z * (16 / KPARTS); kt < (z + 1) * (16 / KPARTS); ++kt) {
    const int kb = kt * 32 + c4 * 4;
    float4 va = *reinterpret_cast<const float4*>(&anchors[(size_t)(i0 + r0) * D_ + kb]);
    float4 vb = *reinterpret_cast<const float4*>(&anchors[(size_t)(i0 + r0 + 32) * D_ + kb]);
    float4 wa = *reinterpret_cast<const float4*>(&anchors[(size_t)(j0 + r0) * D_ + kb]);
    float4 wb = *reinterpret_cast<const float4*>(&anchors[(size_t)(j0 + r0 + 32) * D_ + kb]);
    __syncthreads();
    const int kc = c4 * 4;
    At[kc + 0][r0] = va.x; At[kc + 1][r0] = va.y; At[kc + 2][r0] = va.z; At[kc + 3][r0] = va.w;
    At[kc + 0][r0 + 32] = vb.x; At[kc + 1][r0 + 32] = vb.y; At[kc + 2][r0 + 32] = vb.z; At[kc + 3][r0 + 32] = vb.w;
    Bt[kc + 0][r0] = wa.x; Bt[kc + 1][r0] = wa.y; Bt[kc + 2][r0] = wa.z; Bt[kc + 3][r0] = wa.w;
    Bt[kc + 0][r0 + 32] = wb.x; Bt[kc + 1][r0 + 32] = wb.y; Bt[kc + 2][r0 + 32] = wb.z; Bt[kc + 3][r0 + 32] = wb.w;
    __syncthreads();

#pragma unroll
    for (int kk = 0; kk < 32; ++kk) {
      float4 a = *reinterpret_cast<const float4*>(&At[kk][ty * 4]);
      float4 b = *reinterpret_cast<const float4*>(&Bt[kk][tx * 4]);
      acc[0][0] += a.x * b.x; acc[0][1] += a.x * b.y; acc[0][2] += a.x * b.z; acc[0][3] += a.x * b.w;
      acc[1][0] += a.y * b.x; acc[1][1] += a.y * b.y; acc[1][2] += a.y * b.z; acc[1][3] += a.y * b.w;
      acc[2][0] += a.z * b.x; acc[2][1] += a.z * b.y; acc[2][2] += a.z * b.z; acc[2][3] += a.z * b.w;
      acc[3][0] += a.w * b.x; acc[3][1] += a.w * b.y; acc[3][2] += a.w * b.z; acc[3][3] += a.w * b.w;
    }
  }

#pragma unroll
  for (int m = 0; m < 4; ++m) {
    float4 st;
    st.x = acc[m][0]; st.y = acc[m][1]; st.z = acc[m][2]; st.w = acc[m][3];
    *reinterpret_cast<float4*>(&Gz[(size_t)(i0 + ty * 4 + m) * A_ + j0 + tx * 4]) = st;
  }
}

// ---------------------------------------------------------------------------
// Kernel 2: per-anchor 3-NN + Cayley-Menger det. (unchanged)
// ---------------------------------------------------------------------------
__device__ __forceinline__ void lexmin(float& v, int& j, float ov, int oj) {
  if (ov < v || (ov == v && oj < j)) { v = ov; j = oj; }
}

__global__ __launch_bounds__(64) void nn_det_kernel(
    const float* __restrict__ G, const float* __restrict__ sq,
    float* __restrict__ quality) {
  __shared__ float d2s[16];
  const int i = blockIdx.x;
  const int l = threadIdx.x;
  const float sqi = sq[i];
  const int jb = l * 8;

  float gg[8] = {0.f, 0.f, 0.f, 0.f, 0.f, 0.f, 0.f, 0.f};
#pragma unroll
  for (int z = 0; z < KPARTS; ++z) {
    const float* Grow = G + (size_t)z * A_ * A_ + (size_t)i * A_;
    float4 g0 = *reinterpret_cast<const float4*>(&Grow[jb]);
    float4 g1 = *reinterpret_cast<const float4*>(&Grow[jb + 4]);
    gg[0] += g0.x; gg[1] += g0.y; gg[2] += g0.z; gg[3] += g0.w;
    gg[4] += g1.x; gg[5] += g1.y; gg[6] += g1.z; gg[7] += g1.w;
  }
  float4 s0 = *reinterpret_cast<const float4*>(&sq[jb]);
  float4 s1 = *reinterpret_cast<const float4*>(&sq[jb + 4]);
  float ss[8] = { s0.x, s0.y, s0.z, s0.w, s1.x, s1.y, s1.z, s1.w };

  float dist[8];
#pragma unroll
  for (int q = 0; q < 8; ++q) {
    float d2 = fmaxf(sqi + ss[q] - 2.f * gg[q], 0.f);
    float dd = sqrtf(d2);
    if (jb + q == i) dd += 1e12f;
    dist[q] = dd;
  }

  int nn[NN_];
#pragma unroll
  for (int r = 0; r < NN_; ++r) {
    float bv = 1e30f;
    int bi = 0x7fffffff;
#pragma unroll
    for (int q = 0; q < 8; ++q) lexmin(bv, bi, dist[q], jb + q);
#pragma unroll
    for (int d = 1; d < 64; d <<= 1) {
      float ov = __shfl_xor(bv, d);
      int oi = __shfl_xor(bi, d);
      lexmin(bv, bi, ov, oi);
    }
    nn[r] = bi;
#pragma unroll
    for (int q = 0; q < 8; ++q)
      if (jb + q == bi) dist[q] = 1e30f;
  }

  if (l < 16) {
    const int p = l >> 2, q = l & 3;
    const int pi = (p == 0) ? i : ((p == 1) ? nn[0] : ((p == 2) ? nn[1] : nn[2]));
    const int qi = (q == 0) ? i : ((q == 1) ? nn[0] : ((q == 2) ? nn[1] : nn[2]));
    float d2f;
    if (p == q) {
      d2f = 0.f;
    } else {
      float g = 0.f;
#pragma unroll
      for (int z = 0; z < KPARTS; ++z)
        g += G[(size_t)z * A_ * A_ + (size_t)pi * A_ + qi];
      d2f = sq[pi] + sq[qi] - 2.f * g;
    }
    d2s[l] = d2f;
  }
  __syncthreads();

  if (l == 0) {
    double M[5][5];
    M[0][0] = 0.0;
    for (int q = 1; q < 5; ++q) { M[0][q] = 1.0; M[q][0] = 1.0; }
    for (int p = 0; p < 4; ++p)
      for (int q = 0; q < 4; ++q)
        M[p + 1][q + 1] = (double)d2s[p * 4 + q];

    double det = 1.0;
    for (int c = 0; c < 5; ++c) {
      int piv = c;
      double mx = fabs(M[c][c]);
      for (int r2 = c + 1; r2 < 5; ++r2) {
        double v = fabs(M[r2][c]);
        if (v > mx) { mx = v; piv = r2; }
      }
      if (piv != c) {
        for (int c2 = 0; c2 < 5; ++c2) { double tmp = M[c][c2]; M[c][c2] = M[piv][c2]; M[piv][c2] = tmp; }
        det = -det;
      }
      double pv = M[c][c];
      det *= pv;
      if (pv == 0.0) break;
      for (int r2 = c + 1; r2 < 5; ++r2) {
        double f = M[r2][c] / pv;
        for (int c2 = c; c2 < 5; ++c2) M[r2][c2] -= f * M[c][c2];
      }
    }
    float raw = (float)det;
    float sg = (raw > 0.f) ? 1.f : ((raw < 0.f) ? -1.f : 0.f);
    quality[i] = sg * logf(fabsf(raw) + 1e-12f);
  }
}

// ---------------------------------------------------------------------------
// Kernel 3: normalize quality. (unchanged)
// ---------------------------------------------------------------------------
__global__ __launch_bounds__(A_) void norm_cm_kernel(
    const float* __restrict__ quality, float* __restrict__ cmn) {
  __shared__ float red[A_];
  const int t = threadIdx.x;
  float q = quality[t];
  red[t] = q;
  __syncthreads();
  for (int s = A_ / 2; s > 0; s >>= 1) {
    if (t < s) red[t] += red[t + s];
    __syncthreads();
  }
  float mean = red[0] * (1.0f / A_);
  __syncthreads();
  float dq = q - mean;
  red[t] = dq * dq;
  __syncthreads();
  for (int s = A_ / 2; s > 0; s >>= 1) {
    if (t < s) red[t] += red[t + s];
    __syncthreads();
  }
  float sd = sqrtf(red[0] * (1.0f / (A_ - 1)));
  sd = fmaxf(sd, 1e-8f);
  cmn[t] = dq / sd;
}

// ---------------------------------------------------------------------------
// Kernel 4: FUSED rank + packed-HALF poly-MLP + sigmoid.
// Rank structure byte-identical to round-16 fused (proven 42.9 µs).
// MLP: 8 h2 pairs; clang ext-vector ops -> v_pk_fma_f16 / v_pk_min/max_f16;
// poly-GELU in h2; logit accumulated in f32.
// ---------------------------------------------------------------------------
__global__ __launch_bounds__(A_) void gate_fused(
    const float* __restrict__ tri, const float* __restrict__ cmn,
    const h2* __restrict__ wpk,
    const float* __restrict__ W2, const float* __restrict__ b2,
    float* __restrict__ out) {
  __shared__ int hist[256];
  __shared__ int pref[256];
  __shared__ int cursor[256];
  __shared__ unsigned long long sorted[A_];

  const int n = blockIdx.x;
  const int t = threadIdx.x;

  const float ti = tri[(size_t)n * A_ + t];
  const unsigned long long key =
      ((unsigned long long)__float_as_uint(ti) << 9) | (unsigned)t;
  int b = (int)(ti * 128.0f);
  b = (b < 0) ? 0 : ((b > 255) ? 255 : b);

  if (t < 256) { hist[t] = 0; cursor[t] = 0; }
  __syncthreads();
  atomicAdd(&hist[b], 1);
  __syncthreads();

  if (t < 64) {
    const int b4 = t * 4;
    int h0 = hist[b4 + 0], h1 = hist[b4 + 1], h2v = hist[b4 + 2], h3 = hist[b4 + 3];
    int s = h0 + h1 + h2v + h3;
    int incl = s;
#pragma unroll
    for (int d = 1; d < 64; d <<= 1) {
      int u = __shfl_up(incl, d);
      if (t >= d) incl += u;
    }
    int ex = incl - s;
    pref[b4 + 0] = ex;
    pref[b4 + 1] = ex + h0;
    pref[b4 + 2] = ex + h0 + h1;
    pref[b4 + 3] = ex + h0 + h1 + h2v;
  }
  __syncthreads();

  const int pos = pref[b] + atomicAdd(&cursor[b], 1);
  sorted[pos] = key;
  __syncthreads();

  const int start = pref[b];
  const int len = hist[b];
  int cnt = start;
  for (int m = 0; m < len; ++m) cnt += (sorted[start + m] < key);
  const float rank = (float)cnt * (1.0f / (A_ - 1));

  const float f0 = cmn[t];
  const float f1 = 1.0f - ti;

  h2 f0h; f0h.x = (_Float16)f0;   f0h.y = f0h.x;
  h2 f1h; f1h.x = (_Float16)f1;   f1h.y = f1h.x;
  h2 rkh; rkh.x = (_Float16)rank; rkh.y = rkh.x;

  h2 nine2;  nine2.x = (_Float16)9.0f;  nine2.y = nine2.x;
  h2 three2; three2.x = (_Float16)3.0f; three2.y = three2.x;
  h2 zero2;  zero2.x = (_Float16)0.0f;  zero2.y = zero2.x;
  h2 cA; cA.x = (_Float16)(-2.8012e-4f);  cA.y = cA.x;
  h2 cB; cB.x = (_Float16)(6.4615e-3f);   cB.y = cB.x;
  h2 cC; cC.x = (_Float16)(-6.1073e-2f);  cC.y = cC.x;
  h2 cD; cD.x = (_Float16)(3.96693e-1f);  cD.y = cD.x;
  h2 hf; hf.x = (_Float16)0.5f; hf.y = hf.x;

  float logit = b2[0];
#pragma unroll
  for (int kp = 0; kp < 8; ++kp) {
    h2 x = wpk[kp] * f0h + (wpk[8 + kp] * f1h + (wpk[16 + kp] * rkh + wpk[24 + kp]));
    // poly GELU: 0.5x + min(P(min(x^2,9)), 0.5|x|) + 0.5*max(|x|-3,0)
    h2 u = x * x;
    h2 s = __builtin_elementwise_min(u, nine2);
    h2 p = cA * s + cB;
    p = p * s + cC;
    p = p * s + cD;
    p = p * s;
    h2 ax = __builtin_elementwise_abs(x);
    h2 e = __builtin_elementwise_min(p, hf * ax);
    h2 tail = __builtin_elementwise_max(ax - three2, zero2);
    h2 g = hf * x + (hf * tail + e);
    logit = fmaf(W2[2 * kp],     (float)g.x, logit);
    logit = fmaf(W2[2 * kp + 1], (float)g.y, logit);
  }
  const float eneg = exp2f(logit * -1.44269504088896340736f);
  out[(size_t)n * A_ + t] = __builtin_amdgcn_rcpf(1.0f + eneg);
}

// ---------------------------------------------------------------------------
extern "C" void kernel_launch(void* const* d_in, const int* in_sizes, int n_in,
                              void* d_out, int out_size, void* d_ws, size_t ws_size,
                              hipStream_t stream) {
  // inputs: 0 embedding (unused), 1 anchors, 2 tri, 3 W1, 4 b1, 5 W2, 6 b2
  const float* anchors = (const float*)d_in[1];
  const float* tri     = (const float*)d_in[2];
  const float* W1      = (const float*)d_in[3];
  const float* b1      = (const float*)d_in[4];
  const float* W2      = (const float*)d_in[5];
  const float* b2      = (const float*)d_in[6];
  float* out = (float*)d_out;

  float* G        = (float*)d_ws;                      // KPARTS*A_*A_ (8 MB)
  float* sq       = G + (size_t)KPARTS * A_ * A_;      // A_
  float* quality  = sq + A_;                           // A_
  float* cmn      = quality + A_;                      // A_
  h2* wpk         = (h2*)(cmn + A_);                   // 32 h2 (128 B)

  sq_kernel<<<A_ + 1, 64, 0, stream>>>(anchors, sq, W1, b1, wpk);
  gram_tiled_kernel<<<dim3(8, 8, KPARTS), dim3(16, 16), 0, stream>>>(anchors, G);
  nn_det_kernel<<<A_, 64, 0, stream>>>(G, sq, quality);
  norm_cm_kernel<<<1, A_, 0, stream>>>(quality, cmn);
  gate_fused<<<N_, A_, 0, stream>>>(tri, cmn, wpk, W2, b2, out);
}

// Round 21
// 55.440 us; speedup vs baseline: 1.2662x; 1.0801x over previous
//
#include <hip/hip_runtime.h>
#include <hip/hip_bf16.h>
#include <math.h>

#define N_ 8192
#define A_ 512
#define D_ 512
#define NN_ 3
#define KPARTS 8

typedef _Float16 h2 __attribute__((ext_vector_type(2)));

// ---------------------------------------------------------------------------
// Kernel 1: G_z = partial gram over K-part z (z=0..7), PLUS z==8 slice
// computes sq[i] = ||a_i||^2 (8 anchors/block x 32 lanes, shfl reduce).
// Grid dim3(8,8,9) — sq rides the same launch (one fewer dispatch).
// ---------------------------------------------------------------------------
__global__ __launch_bounds__(256) void gram_tiled_kernel(
    const float* __restrict__ anchors, float* __restrict__ G,
    float* __restrict__ sq) {
  __shared__ float At[32][68];
  __shared__ float Bt[32][68];

  const int tx = threadIdx.x;
  const int ty = threadIdx.y;
  const int tid = ty * 16 + tx;
  const int z  = blockIdx.z;

  if (z == KPARTS) {
    // sq slice: block (bx,by) handles anchors (by*8+bx)*8 .. +7
    const int grp = tid >> 5;          // 0..7
    const int l32 = tid & 31;          // 0..31
    const int a = (blockIdx.y * 8 + blockIdx.x) * 8 + grp;
    const float4* av = reinterpret_cast<const float4*>(anchors + (size_t)a * D_);
    float s = 0.f;
#pragma unroll
    for (int k = 0; k < 4; ++k) {
      float4 v = av[l32 + k * 32];
      s += v.x * v.x + v.y * v.y + v.z * v.z + v.w * v.w;
    }
#pragma unroll
    for (int d = 16; d > 0; d >>= 1) s += __shfl_xor(s, d);
    if (l32 == 0) sq[a] = s;
    return;
  }

  const int i0 = blockIdx.y * 64;
  const int j0 = blockIdx.x * 64;
  float* Gz = G + (size_t)z * A_ * A_;

  const int r0 = tid >> 3;
  const int c4 = tid & 7;

  float acc[4][4];
#pragma unroll
  for (int m = 0; m < 4; ++m)
#pragma unroll
    for (int n = 0; n < 4; ++n) acc[m][n] = 0.f;

  for (int kt = z * (16 / KPARTS); kt < (z + 1) * (16 / KPARTS); ++kt) {
    const int kb = kt * 32 + c4 * 4;
    float4 va = *reinterpret_cast<const float4*>(&anchors[(size_t)(i0 + r0) * D_ + kb]);
    float4 vb = *reinterpret_cast<const float4*>(&anchors[(size_t)(i0 + r0 + 32) * D_ + kb]);
    float4 wa = *reinterpret_cast<const float4*>(&anchors[(size_t)(j0 + r0) * D_ + kb]);
    float4 wb = *reinterpret_cast<const float4*>(&anchors[(size_t)(j0 + r0 + 32) * D_ + kb]);
    __syncthreads();
    const int kc = c4 * 4;
    At[kc + 0][r0] = va.x; At[kc + 1][r0] = va.y; At[kc + 2][r0] = va.z; At[kc + 3][r0] = va.w;
    At[kc + 0][r0 + 32] = vb.x; At[kc + 1][r0 + 32] = vb.y; At[kc + 2][r0 + 32] = vb.z; At[kc + 3][r0 + 32] = vb.w;
    Bt[kc + 0][r0] = wa.x; Bt[kc + 1][r0] = wa.y; Bt[kc + 2][r0] = wa.z; Bt[kc + 3][r0] = wa.w;
    Bt[kc + 0][r0 + 32] = wb.x; Bt[kc + 1][r0 + 32] = wb.y; Bt[kc + 2][r0 + 32] = wb.z; Bt[kc + 3][r0 + 32] = wb.w;
    __syncthreads();

#pragma unroll
    for (int kk = 0; kk < 32; ++kk) {
      float4 a = *reinterpret_cast<const float4*>(&At[kk][ty * 4]);
      float4 b = *reinterpret_cast<const float4*>(&Bt[kk][tx * 4]);
      acc[0][0] += a.x * b.x; acc[0][1] += a.x * b.y; acc[0][2] += a.x * b.z; acc[0][3] += a.x * b.w;
      acc[1][0] += a.y * b.x; acc[1][1] += a.y * b.y; acc[1][2] += a.y * b.z; acc[1][3] += a.y * b.w;
      acc[2][0] += a.z * b.x; acc[2][1] += a.z * b.y; acc[2][2] += a.z * b.z; acc[2][3] += a.z * b.w;
      acc[3][0] += a.w * b.x; acc[3][1] += a.w * b.y; acc[3][2] += a.w * b.z; acc[3][3] += a.w * b.w;
    }
  }

#pragma unroll
  for (int m = 0; m < 4; ++m) {
    float4 st;
    st.x = acc[m][0]; st.y = acc[m][1]; st.z = acc[m][2]; st.w = acc[m][3];
    *reinterpret_cast<float4*>(&Gz[(size_t)(i0 + ty * 4 + m) * A_ + j0 + tx * 4]) = st;
  }
}

// ---------------------------------------------------------------------------
// Kernel 2: per-anchor 3-NN + Cayley-Menger det. (unchanged)
// ---------------------------------------------------------------------------
__device__ __forceinline__ void lexmin(float& v, int& j, float ov, int oj) {
  if (ov < v || (ov == v && oj < j)) { v = ov; j = oj; }
}

__global__ __launch_bounds__(64) void nn_det_kernel(
    const float* __restrict__ G, const float* __restrict__ sq,
    float* __restrict__ quality) {
  __shared__ float d2s[16];
  const int i = blockIdx.x;
  const int l = threadIdx.x;
  const float sqi = sq[i];
  const int jb = l * 8;

  float gg[8] = {0.f, 0.f, 0.f, 0.f, 0.f, 0.f, 0.f, 0.f};
#pragma unroll
  for (int z = 0; z < KPARTS; ++z) {
    const float* Grow = G + (size_t)z * A_ * A_ + (size_t)i * A_;
    float4 g0 = *reinterpret_cast<const float4*>(&Grow[jb]);
    float4 g1 = *reinterpret_cast<const float4*>(&Grow[jb + 4]);
    gg[0] += g0.x; gg[1] += g0.y; gg[2] += g0.z; gg[3] += g0.w;
    gg[4] += g1.x; gg[5] += g1.y; gg[6] += g1.z; gg[7] += g1.w;
  }
  float4 s0 = *reinterpret_cast<const float4*>(&sq[jb]);
  float4 s1 = *reinterpret_cast<const float4*>(&sq[jb + 4]);
  float ss[8] = { s0.x, s0.y, s0.z, s0.w, s1.x, s1.y, s1.z, s1.w };

  float dist[8];
#pragma unroll
  for (int q = 0; q < 8; ++q) {
    float d2 = fmaxf(sqi + ss[q] - 2.f * gg[q], 0.f);
    float dd = sqrtf(d2);
    if (jb + q == i) dd += 1e12f;
    dist[q] = dd;
  }

  int nn[NN_];
#pragma unroll
  for (int r = 0; r < NN_; ++r) {
    float bv = 1e30f;
    int bi = 0x7fffffff;
#pragma unroll
    for (int q = 0; q < 8; ++q) lexmin(bv, bi, dist[q], jb + q);
#pragma unroll
    for (int d = 1; d < 64; d <<= 1) {
      float ov = __shfl_xor(bv, d);
      int oi = __shfl_xor(bi, d);
      lexmin(bv, bi, ov, oi);
    }
    nn[r] = bi;
#pragma unroll
    for (int q = 0; q < 8; ++q)
      if (jb + q == bi) dist[q] = 1e30f;
  }

  if (l < 16) {
    const int p = l >> 2, q = l & 3;
    const int pi = (p == 0) ? i : ((p == 1) ? nn[0] : ((p == 2) ? nn[1] : nn[2]));
    const int qi = (q == 0) ? i : ((q == 1) ? nn[0] : ((q == 2) ? nn[1] : nn[2]));
    float d2f;
    if (p == q) {
      d2f = 0.f;
    } else {
      float g = 0.f;
#pragma unroll
      for (int z = 0; z < KPARTS; ++z)
        g += G[(size_t)z * A_ * A_ + (size_t)pi * A_ + qi];
      d2f = sq[pi] + sq[qi] - 2.f * g;
    }
    d2s[l] = d2f;
  }
  __syncthreads();

  if (l == 0) {
    double M[5][5];
    M[0][0] = 0.0;
    for (int q = 1; q < 5; ++q) { M[0][q] = 1.0; M[q][0] = 1.0; }
    for (int p = 0; p < 4; ++p)
      for (int q = 0; q < 4; ++q)
        M[p + 1][q + 1] = (double)d2s[p * 4 + q];

    double det = 1.0;
    for (int c = 0; c < 5; ++c) {
      int piv = c;
      double mx = fabs(M[c][c]);
      for (int r2 = c + 1; r2 < 5; ++r2) {
        double v = fabs(M[r2][c]);
        if (v > mx) { mx = v; piv = r2; }
      }
      if (piv != c) {
        for (int c2 = 0; c2 < 5; ++c2) { double tmp = M[c][c2]; M[c][c2] = M[piv][c2]; M[piv][c2] = tmp; }
        det = -det;
      }
      double pv = M[c][c];
      det *= pv;
      if (pv == 0.0) break;
      for (int r2 = c + 1; r2 < 5; ++r2) {
        double f = M[r2][c] / pv;
        for (int c2 = c; c2 < 5; ++c2) M[r2][c2] -= f * M[c][c2];
      }
    }
    float raw = (float)det;
    float sg = (raw > 0.f) ? 1.f : ((raw < 0.f) ? -1.f : 0.f);
    quality[i] = sg * logf(fabsf(raw) + 1e-12f);
  }
}

// ---------------------------------------------------------------------------
// Kernel 3: normalize quality; threads 0..7 also pack the MLP weights into
// h2 pairs for the gate (w0p[8] w1p[8] w2p[8] b1p[8]).
// ---------------------------------------------------------------------------
__global__ __launch_bounds__(A_) void norm_cm_kernel(
    const float* __restrict__ quality, float* __restrict__ cmn,
    const float* __restrict__ W1, const float* __restrict__ b1,
    h2* __restrict__ wpk) {
  __shared__ float red[A_];
  const int t = threadIdx.x;

  if (t < 8) {
    h2 a, b, c, d;
    a.x = (_Float16)W1[(2 * t) * 3 + 0]; a.y = (_Float16)W1[(2 * t + 1) * 3 + 0];
    b.x = (_Float16)W1[(2 * t) * 3 + 1]; b.y = (_Float16)W1[(2 * t + 1) * 3 + 1];
    c.x = (_Float16)W1[(2 * t) * 3 + 2]; c.y = (_Float16)W1[(2 * t + 1) * 3 + 2];
    d.x = (_Float16)b1[2 * t];           d.y = (_Float16)b1[2 * t + 1];
    wpk[t] = a; wpk[8 + t] = b; wpk[16 + t] = c; wpk[24 + t] = d;
  }

  float q = quality[t];
  red[t] = q;
  __syncthreads();
  for (int s = A_ / 2; s > 0; s >>= 1) {
    if (t < s) red[t] += red[t + s];
    __syncthreads();
  }
  float mean = red[0] * (1.0f / A_);
  __syncthreads();
  float dq = q - mean;
  red[t] = dq * dq;
  __syncthreads();
  for (int s = A_ / 2; s > 0; s >>= 1) {
    if (t < s) red[t] += red[t + s];
    __syncthreads();
  }
  float sd = sqrtf(red[0] * (1.0f / (A_ - 1)));
  sd = fmaxf(sd, 1e-8f);
  cmn[t] = dq / sd;
}

// ---------------------------------------------------------------------------
// Kernel 4: FUSED rank + packed-HALF poly-MLP + sigmoid.
// (byte-identical to the passing round-20 kernel)
// ---------------------------------------------------------------------------
__global__ __launch_bounds__(A_) void gate_fused(
    const float* __restrict__ tri, const float* __restrict__ cmn,
    const h2* __restrict__ wpk,
    const float* __restrict__ W2, const float* __restrict__ b2,
    float* __restrict__ out) {
  __shared__ int hist[256];
  __shared__ int pref[256];
  __shared__ int cursor[256];
  __shared__ unsigned long long sorted[A_];

  const int n = blockIdx.x;
  const int t = threadIdx.x;

  const float ti = tri[(size_t)n * A_ + t];
  const unsigned long long key =
      ((unsigned long long)__float_as_uint(ti) << 9) | (unsigned)t;
  int b = (int)(ti * 128.0f);
  b = (b < 0) ? 0 : ((b > 255) ? 255 : b);

  if (t < 256) { hist[t] = 0; cursor[t] = 0; }
  __syncthreads();
  atomicAdd(&hist[b], 1);
  __syncthreads();

  if (t < 64) {
    const int b4 = t * 4;
    int h0 = hist[b4 + 0], h1 = hist[b4 + 1], h2v = hist[b4 + 2], h3 = hist[b4 + 3];
    int s = h0 + h1 + h2v + h3;
    int incl = s;
#pragma unroll
    for (int d = 1; d < 64; d <<= 1) {
      int u = __shfl_up(incl, d);
      if (t >= d) incl += u;
    }
    int ex = incl - s;
    pref[b4 + 0] = ex;
    pref[b4 + 1] = ex + h0;
    pref[b4 + 2] = ex + h0 + h1;
    pref[b4 + 3] = ex + h0 + h1 + h2v;
  }
  __syncthreads();

  const int pos = pref[b] + atomicAdd(&cursor[b], 1);
  sorted[pos] = key;
  __syncthreads();

  const int start = pref[b];
  const int len = hist[b];
  int cnt = start;
  for (int m = 0; m < len; ++m) cnt += (sorted[start + m] < key);
  const float rank = (float)cnt * (1.0f / (A_ - 1));

  const float f0 = cmn[t];
  const float f1 = 1.0f - ti;

  h2 f0h; f0h.x = (_Float16)f0;   f0h.y = f0h.x;
  h2 f1h; f1h.x = (_Float16)f1;   f1h.y = f1h.x;
  h2 rkh; rkh.x = (_Float16)rank; rkh.y = rkh.x;

  h2 nine2;  nine2.x = (_Float16)9.0f;  nine2.y = nine2.x;
  h2 three2; three2.x = (_Float16)3.0f; three2.y = three2.x;
  h2 zero2;  zero2.x = (_Float16)0.0f;  zero2.y = zero2.x;
  h2 cA; cA.x = (_Float16)(-2.8012e-4f);  cA.y = cA.x;
  h2 cB; cB.x = (_Float16)(6.4615e-3f);   cB.y = cB.x;
  h2 cC; cC.x = (_Float16)(-6.1073e-2f);  cC.y = cC.x;
  h2 cD; cD.x = (_Float16)(3.96693e-1f);  cD.y = cD.x;
  h2 hf; hf.x = (_Float16)0.5f; hf.y = hf.x;

  float logit = b2[0];
#pragma unroll
  for (int kp = 0; kp < 8; ++kp) {
    h2 x = wpk[kp] * f0h + (wpk[8 + kp] * f1h + (wpk[16 + kp] * rkh + wpk[24 + kp]));
    h2 u = x * x;
    h2 s = __builtin_elementwise_min(u, nine2);
    h2 p = cA * s + cB;
    p = p * s + cC;
    p = p * s + cD;
    p = p * s;
    h2 ax = __builtin_elementwise_abs(x);
    h2 e = __builtin_elementwise_min(p, hf * ax);
    h2 tail = __builtin_elementwise_max(ax - three2, zero2);
    h2 g = hf * x + (hf * tail + e);
    logit = fmaf(W2[2 * kp],     (float)g.x, logit);
    logit = fmaf(W2[2 * kp + 1], (float)g.y, logit);
  }
  const float eneg = exp2f(logit * -1.44269504088896340736f);
  out[(size_t)n * A_ + t] = __builtin_amdgcn_rcpf(1.0f + eneg);
}

// ---------------------------------------------------------------------------
extern "C" void kernel_launch(void* const* d_in, const int* in_sizes, int n_in,
                              void* d_out, int out_size, void* d_ws, size_t ws_size,
                              hipStream_t stream) {
  // inputs: 0 embedding (unused), 1 anchors, 2 tri, 3 W1, 4 b1, 5 W2, 6 b2
  const float* anchors = (const float*)d_in[1];
  const float* tri     = (const float*)d_in[2];
  const float* W1      = (const float*)d_in[3];
  const float* b1      = (const float*)d_in[4];
  const float* W2      = (const float*)d_in[5];
  const float* b2      = (const float*)d_in[6];
  float* out = (float*)d_out;

  float* G        = (float*)d_ws;                      // KPARTS*A_*A_ (8 MB)
  float* sq       = G + (size_t)KPARTS * A_ * A_;      // A_
  float* quality  = sq + A_;                           // A_
  float* cmn      = quality + A_;                      // A_
  h2* wpk         = (h2*)(cmn + A_);                   // 32 h2 (128 B)

  gram_tiled_kernel<<<dim3(8, 8, KPARTS + 1), dim3(16, 16), 0, stream>>>(anchors, G, sq);
  nn_det_kernel<<<A_, 64, 0, stream>>>(G, sq, quality);
  norm_cm_kernel<<<1, A_, 0, stream>>>(quality, cmn, W1, b1, wpk);
  gate_fused<<<N_, A_, 0, stream>>>(tri, cmn, wpk, W2, b2, out);
}